// Round 1
// baseline (412.607 us; speedup 1.0000x reference)
//
#include <hip/hip_runtime.h>

// LSTM cell fused kernel for MI355X (gfx950).
// B=8192, IN=1024, HID=1024, K = IN+HID = 2048.
// Plan: prep1 packs [Z|h_prev] -> bf16 A[8192][2048]; prep2 transposes weights
// to Wt[g][n][k] bf16; gemm kernel computes all 4 gates per 64x64 tile
// (wave w <-> gate w), fuses bias+sigmoid/tanh+cell update in epilogue.

#define BDIM 8192
#define KDIM 2048
#define NDIM 1024

typedef __bf16 bf16x8 __attribute__((ext_vector_type(8)));
typedef __bf16 bf16x4 __attribute__((ext_vector_type(4)));
typedef float  f32x4  __attribute__((ext_vector_type(4)));

__device__ __forceinline__ void async_cp16(const void* g, void* l) {
    // global -> LDS direct copy, 16B per lane. LDS dest is wave-uniform base;
    // HW adds lane*16.
    __builtin_amdgcn_global_load_lds((__attribute__((address_space(1))) void*)g,
                                     (__attribute__((address_space(3))) void*)l,
                                     16, 0, 0);
}

__device__ __forceinline__ float sigm(float x) { return 1.f / (1.f + __expf(-x)); }
// saturation-safe tanh: x->+inf => 1, x->-inf => -1 (no inf/inf NaN)
__device__ __forceinline__ float tanh_fast(float x) { return 1.f - 2.f / (1.f + __expf(2.f * x)); }

// ---------------- prep 1: A = bf16([Z | h_prev]) ----------------
__global__ void build_A_kernel(const float* __restrict__ Z, const float* __restrict__ H,
                               __bf16* __restrict__ A) {
    int idx = blockIdx.x * 256 + threadIdx.x;   // one float4 (4 elems) per thread
    int row = idx >> 9;                          // 512 quads per 2048-col row
    int q   = idx & 511;
    float4 v;
    if (q < 256) v = ((const float4*)Z)[row * 256 + q];
    else         v = ((const float4*)H)[row * 256 + (q - 256)];
    bf16x4 o = { (__bf16)v.x, (__bf16)v.y, (__bf16)v.z, (__bf16)v.w };
    ((bf16x4*)A)[idx] = o;
}

// ---------------- prep 2: Wt[g][n][k] = bf16(W_g[k][n]) ----------------
__global__ void transpose_W_kernel(const float* __restrict__ Wi, const float* __restrict__ Wf,
                                   const float* __restrict__ Wo, const float* __restrict__ Wg,
                                   __bf16* __restrict__ Wt) {
    __shared__ float t[32][33];   // +1 pad: conflict-free transpose
    int g = blockIdx.z;
    const float* W = (g == 0) ? Wi : (g == 1) ? Wf : (g == 2) ? Wo : Wg;
    int k0 = blockIdx.x * 32, n0 = blockIdx.y * 32;
    int c = threadIdx.x & 31, r8 = threadIdx.x >> 5;
    #pragma unroll
    for (int j = 0; j < 4; ++j) {
        int r = r8 + j * 8;
        t[r][c] = W[(size_t)(k0 + r) * NDIM + (n0 + c)];   // coalesced read
    }
    __syncthreads();
    __bf16* out = Wt + (size_t)g * NDIM * KDIM;
    #pragma unroll
    for (int j = 0; j < 4; ++j) {
        int r = r8 + j * 8;
        out[(size_t)(n0 + r) * KDIM + (k0 + c)] = (__bf16)t[c][r];   // coalesced write
    }
}

// ---------------- fused 4-gate GEMM + LSTM epilogue ----------------
// Tile: 64 rows (batch) x 64 cols (hidden) per block, 256 threads = 4 waves.
// Wave w computes gate w over the whole tile: 4x4 frags of 16x16x32 bf16 MFMA.
// LDS: As 64x32 (4KB) + Bs[4] 64x32 each (16KB), XOR-swizzled 16B chunks so
// ds_read_b128 frag reads are 2-way (free). Epilogue overlays Bs with 16KB of
// fp32 gate values, processed in 4 row-chunks of 16x64.
__global__ void lstm_gemm_kernel(const __bf16* __restrict__ A, const __bf16* __restrict__ Wt,
                                 const float* __restrict__ b_i, const float* __restrict__ b_f,
                                 const float* __restrict__ b_o, const float* __restrict__ b_g,
                                 const float* __restrict__ c_prev, float* __restrict__ out) {
    __shared__ char smem[20480];
    __bf16* As = (__bf16*)smem;              // 4 KB
    __bf16* Bs = (__bf16*)(smem + 4096);     // 16 KB (4 gates x 64x32 bf16)
    float*  Ep = (float*)(smem + 4096);      // epilogue overlay: 4 x (16x64) f32

    const int tid  = threadIdx.x;
    const int wave = tid >> 6;      // = gate id
    const int lane = tid & 63;
    const int m0 = blockIdx.y * 64;
    const int n0 = blockIdx.x * 64;

    // --- staging geometry: lane l stages 16B chunk; swizzle c = (l&3) ^ ((l>>3)&3)
    const int srow   = lane >> 2;                       // local row 0..15 per instr
    const int schunk = (lane & 3) ^ ((lane >> 3) & 3);  // which 16B chunk of the row

    const __bf16* Aglob = A + (size_t)(m0 + wave * 16 + srow) * KDIM + schunk * 8;
    __bf16* AldsBase = As + wave * 512;                 // wave-uniform LDS base

    const __bf16* WtG = Wt + (size_t)wave * NDIM * KDIM;
    const __bf16* Bglob[4];
    __bf16* BldsBase[4];
    #pragma unroll
    for (int t = 0; t < 4; ++t) {
        Bglob[t] = WtG + (size_t)(n0 + t * 16 + srow) * KDIM + schunk * 8;
        BldsBase[t] = Bs + wave * 2048 + t * 512;
    }

    // --- fragment read geometry (A[m=lane&15][k=quad*8+j], B^T[n=lane&15][k=quad*8+j])
    const int l15  = lane & 15;
    const int quad = lane >> 4;
    int aoff[4];
    #pragma unroll
    for (int t = 0; t < 4; ++t) {
        int r = t * 16 + l15;
        aoff[t] = r * 32 + ((quad ^ ((r >> 1) & 3)) * 8);   // element offset, 16B aligned
    }

    f32x4 acc[4][4];
    #pragma unroll
    for (int i = 0; i < 4; ++i)
        #pragma unroll
        for (int j = 0; j < 4; ++j) acc[i][j] = (f32x4){0.f, 0.f, 0.f, 0.f};

    for (int k0 = 0; k0 < KDIM; k0 += 32) {
        // stage A tile (each wave 1KB) + this wave's gate B tile (4KB)
        async_cp16(Aglob + k0, AldsBase);
        #pragma unroll
        for (int t = 0; t < 4; ++t) async_cp16(Bglob[t] + k0, BldsBase[t]);
        __syncthreads();   // drains vmcnt, LDS visible to all waves

        bf16x8 af[4], bfr[4];
        #pragma unroll
        for (int t = 0; t < 4; ++t) af[t]  = *(const bf16x8*)(As + aoff[t]);
        #pragma unroll
        for (int t = 0; t < 4; ++t) bfr[t] = *(const bf16x8*)(Bs + wave * 2048 + aoff[t]);

        #pragma unroll
        for (int mt = 0; mt < 4; ++mt)
            #pragma unroll
            for (int nt = 0; nt < 4; ++nt)
                acc[mt][nt] = __builtin_amdgcn_mfma_f32_16x16x32_bf16(af[mt], bfr[nt], acc[mt][nt], 0, 0, 0);
        __syncthreads();   // protect LDS before next overwrite (and before epilogue overlay)
    }

    // --- epilogue: bias per wave's gate, then combine via LDS in 4 row-chunks
    const float* bias = (wave == 0) ? b_i : (wave == 1) ? b_f : (wave == 2) ? b_o : b_g;
    float bv[4];
    #pragma unroll
    for (int nt = 0; nt < 4; ++nt) bv[nt] = bias[n0 + nt * 16 + l15];

    #pragma unroll
    for (int j = 0; j < 4; ++j) {    // j = mt row-chunk: rows [j*16, j*16+16)
        // C/D layout: row = quad*4 + reg, col = nt*16 + l15
        #pragma unroll
        for (int nt = 0; nt < 4; ++nt)
            #pragma unroll
            for (int r = 0; r < 4; ++r)
                Ep[wave * 1024 + (quad * 4 + r) * 64 + nt * 16 + l15] = acc[j][nt][r] + bv[nt];
        __syncthreads();

        #pragma unroll
        for (int e = 0; e < 4; ++e) {
            int idx = tid + e * 256;           // 0..1023 over 16x64 chunk
            int rl = idx >> 6, cl = idx & 63;
            float gi = sigm(Ep[0 * 1024 + idx]);
            float gf = sigm(Ep[1 * 1024 + idx]);
            float go = sigm(Ep[2 * 1024 + idx]);
            float gg = tanh_fast(Ep[3 * 1024 + idx]);
            size_t gpos = (size_t)(m0 + j * 16 + rl) * NDIM + (n0 + cl);
            float cp = c_prev[gpos];
            float cv = gf * cp + gi * gg;
            float hv = go * tanh_fast(cv);
            out[gpos] = hv;                                  // h
            out[(size_t)BDIM * NDIM + gpos] = cv;            // c
        }
        __syncthreads();
    }
}

extern "C" void kernel_launch(void* const* d_in, const int* in_sizes, int n_in,
                              void* d_out, int out_size, void* d_ws, size_t ws_size,
                              hipStream_t stream) {
    const float* Z   = (const float*)d_in[0];
    const float* H   = (const float*)d_in[1];
    const float* Cp  = (const float*)d_in[2];
    const float* Wi  = (const float*)d_in[3];
    const float* bi  = (const float*)d_in[4];
    const float* Wf  = (const float*)d_in[5];
    const float* bf  = (const float*)d_in[6];
    const float* Wo  = (const float*)d_in[7];
    const float* bo  = (const float*)d_in[8];
    const float* Wg  = (const float*)d_in[9];
    const float* bg  = (const float*)d_in[10];

    __bf16* Acomb = (__bf16*)d_ws;                                   // 32 MB
    __bf16* Wt    = (__bf16*)((char*)d_ws + (size_t)33554432);       // 16 MB

    build_A_kernel<<<(BDIM * KDIM / 4) / 256, 256, 0, stream>>>(Z, H, Acomb);
    transpose_W_kernel<<<dim3(KDIM / 32, NDIM / 32, 4), 256, 0, stream>>>(Wi, Wf, Wo, Wg, Wt);
    lstm_gemm_kernel<<<dim3(NDIM / 64, BDIM / 64), 256, 0, stream>>>(
        Acomb, Wt, bi, bf, bo, bg, Cp, (float*)d_out);
}

// Round 2
// 341.927 us; speedup vs baseline: 1.2067x; 1.2067x over previous
//
#include <hip/hip_runtime.h>

// LSTM cell fused, round 2: single 8192 x 4096 x 2048 bf16 GEMM (m97-style
// 128x128 tile) over gate-interleaved weights. Cat-column layout:
//   r_cat = n_outer*128 + gate*32 + n_inner   (n_hid = n_outer*32 + n_inner)
// so one 128-wide tile holds i,f,o,g for 32 hidden cols -> fused epilogue.

#define BDIM 8192
#define KDIM 2048
#define NDIM 1024
#define NCAT 4096

typedef __bf16 bf16x8 __attribute__((ext_vector_type(8)));
typedef __bf16 bf16x4 __attribute__((ext_vector_type(4)));
typedef float  f32x4  __attribute__((ext_vector_type(4)));

__device__ __forceinline__ void async_cp16(const void* g, void* l) {
    __builtin_amdgcn_global_load_lds((__attribute__((address_space(1))) void*)g,
                                     (__attribute__((address_space(3))) void*)l,
                                     16, 0, 0);
}

__device__ __forceinline__ float sigm(float x) { return 1.f / (1.f + __expf(-x)); }
__device__ __forceinline__ float tanh_fast(float x) { return 1.f - 2.f / (1.f + __expf(2.f * x)); }

// ---------------- merged prep: A pack + weight transpose ----------------
// blocks [0, 16384): A = bf16([Z | h_prev]), one float4 per thread.
// blocks [16384, 24576): Wt[r_cat][k] = bf16(W_gate[k][n_hid]), 32x32 tiles.
__global__ void prep_kernel(const float* __restrict__ Z, const float* __restrict__ H,
                            const float* __restrict__ Wi, const float* __restrict__ Wf,
                            const float* __restrict__ Wo, const float* __restrict__ Wg,
                            __bf16* __restrict__ A, __bf16* __restrict__ Wt) {
    __shared__ float t[32][33];
    int bid = blockIdx.x;
    if (bid < 16384) {
        int idx = bid * 256 + threadIdx.x;
        int row = idx >> 9;
        int q   = idx & 511;
        float4 v;
        if (q < 256) v = ((const float4*)Z)[row * 256 + q];
        else         v = ((const float4*)H)[row * 256 + (q - 256)];
        bf16x4 o = { (__bf16)v.x, (__bf16)v.y, (__bf16)v.z, (__bf16)v.w };
        ((bf16x4*)A)[idx] = o;
    } else {
        int id  = bid - 16384;
        int g   = id >> 11;           // 2048 blocks per gate = 64 kb x 32 nb
        int rem = id & 2047;
        int k0  = (rem & 63) * 32;
        int n0  = (rem >> 6) * 32;
        const float* W = (g == 0) ? Wi : (g == 1) ? Wf : (g == 2) ? Wo : Wg;
        int c = threadIdx.x & 31, r8 = threadIdx.x >> 5;
        #pragma unroll
        for (int j = 0; j < 4; ++j) {
            int r = r8 + j * 8;
            t[r][c] = W[(size_t)(k0 + r) * NDIM + (n0 + c)];
        }
        __syncthreads();
        size_t outRow = (size_t)((n0 >> 5) * 128 + g * 32);
        #pragma unroll
        for (int j = 0; j < 4; ++j) {
            int r = r8 + j * 8;
            Wt[(outRow + r) * KDIM + (k0 + c)] = (__bf16)t[c][r];
        }
    }
}

// ---------------- 128x128 GEMM + fused LSTM epilogue ----------------
// 256 threads = 4 waves; wave (wr=w>>1, wc=w&1) owns 64x64 quadrant as 4x4
// frags of mfma_f32_16x16x32_bf16. BK=32. LDS: As 128x32 (8KB) + Bs 128x32
// (8KB), staged via global_load_lds dwordx4 with XOR chunk swizzle
// (chunk_pos = chunk ^ ((row>>1)&3)) so frag ds_read_b128 is 2-way (free).
// Epilogue overlays LDS with Ep[64][132] f32, two 64-row chunks.
__global__ __launch_bounds__(256, 3)
void lstm_gemm_kernel(const __bf16* __restrict__ A, const __bf16* __restrict__ Wt,
                      const float* __restrict__ b_i, const float* __restrict__ b_f,
                      const float* __restrict__ b_o, const float* __restrict__ b_g,
                      const float* __restrict__ c_prev, float* __restrict__ out) {
    __shared__ char smem[33792];              // max(16KB gemm, 64*132*4 epilogue)
    __bf16* As = (__bf16*)smem;               // 8 KB
    __bf16* Bs = (__bf16*)(smem + 8192);      // 8 KB
    float*  Ep = (float*)smem;                // overlay

    const int tid  = threadIdx.x;
    const int wave = tid >> 6;
    const int lane = tid & 63;
    const int wr = wave >> 1, wc = wave & 1;
    const int bx = blockIdx.x;                // n_outer: hidden cols [bx*32, bx*32+32)
    const int m0 = blockIdx.y * 128;
    const int ncat0 = bx * 128;

    // staging: group g = wave*2 + i stages rows [g*16, g*16+16); lane l ->
    // row g*16 + (l>>2), LDS chunk l&3, global chunk (l&3)^((l>>3)&3).
    const int srow   = lane >> 2;
    const int schunk = (lane & 3) ^ ((lane >> 3) & 3);
    const __bf16* Ag[2]; __bf16* Al[2];
    const __bf16* Bg[2]; __bf16* Bl[2];
    #pragma unroll
    for (int i = 0; i < 2; ++i) {
        int grp = wave * 2 + i;
        Ag[i] = A  + (size_t)(m0    + grp * 16 + srow) * KDIM + schunk * 8;
        Bg[i] = Wt + (size_t)(ncat0 + grp * 16 + srow) * KDIM + schunk * 8;
        Al[i] = As + grp * 512;               // wave-uniform; HW adds lane*16B
        Bl[i] = Bs + grp * 512;
    }

    // fragment geometry: A[m=l15][k=quad*8+j]; swizzled chunk sel = (l15>>1)&3
    const int l15  = lane & 15;
    const int quad = lane >> 4;
    const int ksw  = (quad ^ ((l15 >> 1) & 3)) * 8;
    int aoff[4], boff[4];
    #pragma unroll
    for (int t = 0; t < 4; ++t) {
        aoff[t] = (wr * 64 + t * 16 + l15) * 32 + ksw;
        boff[t] = (wc * 64 + t * 16 + l15) * 32 + ksw;
    }

    f32x4 acc[4][4];
    #pragma unroll
    for (int i = 0; i < 4; ++i)
        #pragma unroll
        for (int j = 0; j < 4; ++j) acc[i][j] = (f32x4){0.f, 0.f, 0.f, 0.f};

    for (int k0 = 0; k0 < KDIM; k0 += 32) {
        async_cp16(Ag[0] + k0, Al[0]);
        async_cp16(Ag[1] + k0, Al[1]);
        async_cp16(Bg[0] + k0, Bl[0]);
        async_cp16(Bg[1] + k0, Bl[1]);
        __syncthreads();

        bf16x8 af[4], bfr[4];
        #pragma unroll
        for (int t = 0; t < 4; ++t) af[t]  = *(const bf16x8*)(As + aoff[t]);
        #pragma unroll
        for (int t = 0; t < 4; ++t) bfr[t] = *(const bf16x8*)(Bs + boff[t]);

        #pragma unroll
        for (int mt = 0; mt < 4; ++mt)
            #pragma unroll
            for (int nt = 0; nt < 4; ++nt)
                acc[mt][nt] = __builtin_amdgcn_mfma_f32_16x16x32_bf16(af[mt], bfr[nt], acc[mt][nt], 0, 0, 0);
        __syncthreads();
    }

    // --- epilogue ---
    // wave's cat-col = wc*64 + nt*16 + l15 -> gate = wc*2 + (nt>>1),
    // n_inner = (nt&1)*16 + l15
    const float* bias_lo = (wc == 0) ? b_i : b_o;   // gate wc*2
    const float* bias_hi = (wc == 0) ? b_f : b_g;   // gate wc*2+1
    float bv[4];
    bv[0] = bias_lo[bx * 32 + l15];
    bv[1] = bias_lo[bx * 32 + 16 + l15];
    bv[2] = bias_hi[bx * 32 + l15];
    bv[3] = bias_hi[bx * 32 + 16 + l15];

    #pragma unroll
    for (int c = 0; c < 2; ++c) {    // chunk c: tile rows [c*64, c*64+64)
        __syncthreads();
        if (wr == c) {
            #pragma unroll
            for (int mt = 0; mt < 4; ++mt)
                #pragma unroll
                for (int nt = 0; nt < 4; ++nt)
                    #pragma unroll
                    for (int r = 0; r < 4; ++r)
                        Ep[(mt * 16 + quad * 4 + r) * 132 + wc * 64 + nt * 16 + l15] =
                            acc[mt][nt][r] + bv[nt];
        }
        __syncthreads();

        #pragma unroll
        for (int e = 0; e < 8; ++e) {
            int idx = tid + e * 256;          // 0..2047 over 64 rows x 32 cols
            int row = idx >> 5, n = idx & 31;
            float gi = sigm(Ep[row * 132 + n]);
            float gf = sigm(Ep[row * 132 + 32 + n]);
            float go = sigm(Ep[row * 132 + 64 + n]);
            float gg = tanh_fast(Ep[row * 132 + 96 + n]);
            size_t pos = (size_t)(m0 + c * 64 + row) * NDIM + bx * 32 + n;
            float cp = c_prev[pos];
            float cv = gf * cp + gi * gg;
            out[pos] = go * tanh_fast(cv);                 // h
            out[(size_t)BDIM * NDIM + pos] = cv;           // c
        }
    }
}

extern "C" void kernel_launch(void* const* d_in, const int* in_sizes, int n_in,
                              void* d_out, int out_size, void* d_ws, size_t ws_size,
                              hipStream_t stream) {
    const float* Z  = (const float*)d_in[0];
    const float* H  = (const float*)d_in[1];
    const float* Cp = (const float*)d_in[2];
    const float* Wi = (const float*)d_in[3];
    const float* bi = (const float*)d_in[4];
    const float* Wf = (const float*)d_in[5];
    const float* bf = (const float*)d_in[6];
    const float* Wo = (const float*)d_in[7];
    const float* bo = (const float*)d_in[8];
    const float* Wg = (const float*)d_in[9];
    const float* bg = (const float*)d_in[10];

    __bf16* Acomb = (__bf16*)d_ws;                              // 32 MB
    __bf16* Wt    = (__bf16*)((char*)d_ws + (size_t)33554432);  // 16 MB

    prep_kernel<<<16384 + 8192, 256, 0, stream>>>(Z, H, Wi, Wf, Wo, Wg, Acomb, Wt);
    lstm_gemm_kernel<<<dim3(NCAT / 128, BDIM / 128), 256, 0, stream>>>(
        Acomb, Wt, bi, bf, bo, bg, Cp, (float*)d_out);
}

// Round 3
// 331.823 us; speedup vs baseline: 1.2435x; 1.0304x over previous
//
#include <hip/hip_runtime.h>

// LSTM cell fused, round 3: 8192 x 4096 x 2048 bf16 GEMM, 128x128 tile,
// BK=64 as two conflict-free BK=32 half-stages per barrier (32 barriers),
// 4 blocks/CU (32KB LDS, launch_bounds(256,4)), XCD-chunked block swizzle
// (each XCD keeps a 2MB Wt column-chunk L2-resident).

#define BDIM 8192
#define KDIM 2048
#define NDIM 1024
#define NCAT 4096

typedef __bf16 bf16x8 __attribute__((ext_vector_type(8)));
typedef __bf16 bf16x4 __attribute__((ext_vector_type(4)));
typedef float  f32x4  __attribute__((ext_vector_type(4)));

__device__ __forceinline__ void async_cp16(const void* g, void* l) {
    __builtin_amdgcn_global_load_lds((__attribute__((address_space(1))) void*)g,
                                     (__attribute__((address_space(3))) void*)l,
                                     16, 0, 0);
}

__device__ __forceinline__ float sigm(float x) { return 1.f / (1.f + __expf(-x)); }
__device__ __forceinline__ float tanh_fast(float x) { return 1.f - 2.f / (1.f + __expf(2.f * x)); }

// ---------------- merged prep: A pack + weight transpose ----------------
__global__ void prep_kernel(const float* __restrict__ Z, const float* __restrict__ H,
                            const float* __restrict__ Wi, const float* __restrict__ Wf,
                            const float* __restrict__ Wo, const float* __restrict__ Wg,
                            __bf16* __restrict__ A, __bf16* __restrict__ Wt) {
    __shared__ float t[32][33];
    int bid = blockIdx.x;
    if (bid < 16384) {
        int idx = bid * 256 + threadIdx.x;
        int row = idx >> 9;
        int q   = idx & 511;
        float4 v;
        if (q < 256) v = ((const float4*)Z)[row * 256 + q];
        else         v = ((const float4*)H)[row * 256 + (q - 256)];
        bf16x4 o = { (__bf16)v.x, (__bf16)v.y, (__bf16)v.z, (__bf16)v.w };
        ((bf16x4*)A)[idx] = o;
    } else {
        int id  = bid - 16384;
        int g   = id >> 11;
        int rem = id & 2047;
        int k0  = (rem & 63) * 32;
        int n0  = (rem >> 6) * 32;
        const float* W = (g == 0) ? Wi : (g == 1) ? Wf : (g == 2) ? Wo : Wg;
        int c = threadIdx.x & 31, r8 = threadIdx.x >> 5;
        #pragma unroll
        for (int j = 0; j < 4; ++j) {
            int r = r8 + j * 8;
            t[r][c] = W[(size_t)(k0 + r) * NDIM + (n0 + c)];
        }
        __syncthreads();
        size_t outRow = (size_t)((n0 >> 5) * 128 + g * 32);
        #pragma unroll
        for (int j = 0; j < 4; ++j) {
            int r = r8 + j * 8;
            Wt[(outRow + r) * KDIM + (k0 + c)] = (__bf16)t[c][r];
        }
    }
}

// ---------------- 128x128 GEMM + fused LSTM epilogue ----------------
// LDS layout (32KB): As = 2 halves x [128 rows x 32 k] bf16 (8KB each),
// Bs likewise at +16KB. Each half uses the verified BK=32 XOR-chunk swizzle
// (row stride 64B -> row parity spreads banks; 0 conflicts measured).
// Epilogue overlays LDS with Ep[32][132] f32 (16.9KB), 4 row-chunks.
__global__ __launch_bounds__(256, 4)
void lstm_gemm_kernel(const __bf16* __restrict__ A, const __bf16* __restrict__ Wt,
                      const float* __restrict__ b_i, const float* __restrict__ b_f,
                      const float* __restrict__ b_o, const float* __restrict__ b_g,
                      const float* __restrict__ c_prev, float* __restrict__ out) {
    __shared__ char smem[32768];
    __bf16* As = (__bf16*)smem;               // 16 KB (2 x 8KB halves)
    __bf16* Bs = (__bf16*)(smem + 16384);     // 16 KB
    float*  Ep = (float*)smem;                // epilogue overlay 32x132 f32

    const int tid  = threadIdx.x;
    const int wave = tid >> 6;
    const int lane = tid & 63;
    const int wr = wave >> 1, wc = wave & 1;

    // XCD swizzle: assume consecutive blockIdx round-robin XCDs. XCD x owns
    // bx in [x*4, x*4+4) (2MB of Wt -> L2-resident), sweeping all by.
    const int bid = blockIdx.x;
    const int bx = (bid & 7) * 4 + ((bid >> 3) & 3);
    const int by = bid >> 5;
    const int m0 = by * 128;
    const int ncat0 = bx * 128;

    // staging: group g = wave*2+i covers rows [g*16, g*16+16) of one half;
    // lane l -> row g*16 + (l>>2), LDS chunk l&3, global chunk (l&3)^((l>>3)&3).
    const int srow   = lane >> 2;
    const int schunk = (lane & 3) ^ ((lane >> 3) & 3);
    const __bf16* Ag[2]; __bf16* Al[2];
    const __bf16* Bg[2]; __bf16* Bl[2];
    #pragma unroll
    for (int i = 0; i < 2; ++i) {
        int grp = wave * 2 + i;
        Ag[i] = A  + (size_t)(m0    + grp * 16 + srow) * KDIM + schunk * 8;
        Bg[i] = Wt + (size_t)(ncat0 + grp * 16 + srow) * KDIM + schunk * 8;
        Al[i] = As + grp * 512;
        Bl[i] = Bs + grp * 512;
    }

    // fragment geometry within a half: A[m=l15][k=quad*8+j], swizzled chunk
    const int l15  = lane & 15;
    const int quad = lane >> 4;
    const int ksw  = (quad ^ ((l15 >> 1) & 3)) * 8;
    int aoff[4], boff[4];
    #pragma unroll
    for (int t = 0; t < 4; ++t) {
        aoff[t] = (wr * 64 + t * 16 + l15) * 32 + ksw;
        boff[t] = (wc * 64 + t * 16 + l15) * 32 + ksw;
    }

    f32x4 acc[4][4];
    #pragma unroll
    for (int i = 0; i < 4; ++i)
        #pragma unroll
        for (int j = 0; j < 4; ++j) acc[i][j] = (f32x4){0.f, 0.f, 0.f, 0.f};

    for (int k0 = 0; k0 < KDIM; k0 += 64) {
        #pragma unroll
        for (int h = 0; h < 2; ++h)
            #pragma unroll
            for (int i = 0; i < 2; ++i) {
                async_cp16(Ag[i] + k0 + h * 32, Al[i] + h * 4096);
                async_cp16(Bg[i] + k0 + h * 32, Bl[i] + h * 4096);
            }
        __syncthreads();

        #pragma unroll
        for (int h = 0; h < 2; ++h) {
            bf16x8 af[4], bfr[4];
            #pragma unroll
            for (int t = 0; t < 4; ++t) af[t]  = *(const bf16x8*)(As + h * 4096 + aoff[t]);
            #pragma unroll
            for (int t = 0; t < 4; ++t) bfr[t] = *(const bf16x8*)(Bs + h * 4096 + boff[t]);
            #pragma unroll
            for (int mt = 0; mt < 4; ++mt)
                #pragma unroll
                for (int nt = 0; nt < 4; ++nt)
                    acc[mt][nt] = __builtin_amdgcn_mfma_f32_16x16x32_bf16(af[mt], bfr[nt], acc[mt][nt], 0, 0, 0);
        }
        __syncthreads();
    }

    // --- epilogue: 4 chunks of 32 rows ---
    // wave cat-col = wc*64 + nt*16 + l15 -> gate = wc*2 + (nt>>1)
    const float* bias_lo = (wc == 0) ? b_i : b_o;
    const float* bias_hi = (wc == 0) ? b_f : b_g;
    float bv[4];
    bv[0] = bias_lo[bx * 32 + l15];
    bv[1] = bias_lo[bx * 32 + 16 + l15];
    bv[2] = bias_hi[bx * 32 + l15];
    bv[3] = bias_hi[bx * 32 + 16 + l15];

    #pragma unroll
    for (int c = 0; c < 4; ++c) {     // chunk c: tile rows [c*32, c*32+32)
        __syncthreads();
        if (wr == (c >> 1)) {
            #pragma unroll
            for (int mi = 0; mi < 2; ++mi) {
                int mt = (c & 1) * 2 + mi;
                #pragma unroll
                for (int nt = 0; nt < 4; ++nt)
                    #pragma unroll
                    for (int r = 0; r < 4; ++r)
                        Ep[(mi * 16 + quad * 4 + r) * 132 + wc * 64 + nt * 16 + l15] =
                            acc[mt][nt][r] + bv[nt];
            }
        }
        __syncthreads();

        #pragma unroll
        for (int e = 0; e < 4; ++e) {
            int idx = tid + e * 256;          // 0..1023 over 32 rows x 32 cols
            int row = idx >> 5, n = idx & 31;
            float gi = sigm(Ep[row * 132 + n]);
            float gf = sigm(Ep[row * 132 + 32 + n]);
            float go = sigm(Ep[row * 132 + 64 + n]);
            float gg = tanh_fast(Ep[row * 132 + 96 + n]);
            size_t pos = (size_t)(m0 + c * 32 + row) * NDIM + bx * 32 + n;
            float cp = c_prev[pos];
            float cv = gf * cp + gi * gg;
            out[pos] = go * tanh_fast(cv);                 // h
            out[(size_t)BDIM * NDIM + pos] = cv;           // c
        }
    }
}

extern "C" void kernel_launch(void* const* d_in, const int* in_sizes, int n_in,
                              void* d_out, int out_size, void* d_ws, size_t ws_size,
                              hipStream_t stream) {
    const float* Z  = (const float*)d_in[0];
    const float* H  = (const float*)d_in[1];
    const float* Cp = (const float*)d_in[2];
    const float* Wi = (const float*)d_in[3];
    const float* bi = (const float*)d_in[4];
    const float* Wf = (const float*)d_in[5];
    const float* bf = (const float*)d_in[6];
    const float* Wo = (const float*)d_in[7];
    const float* bo = (const float*)d_in[8];
    const float* Wg = (const float*)d_in[9];
    const float* bg = (const float*)d_in[10];

    __bf16* Acomb = (__bf16*)d_ws;                              // 32 MB
    __bf16* Wt    = (__bf16*)((char*)d_ws + (size_t)33554432);  // 16 MB

    prep_kernel<<<16384 + 8192, 256, 0, stream>>>(Z, H, Wi, Wf, Wo, Wg, Acomb, Wt);
    lstm_gemm_kernel<<<dim3(NCAT / 128 * BDIM / 128), 256, 0, stream>>>(
        Acomb, Wt, bi, bf, bo, bg, Cp, (float*)d_out);
}